// Round 9
// baseline (204.610 us; speedup 1.0000x reference)
//
#include <hip/hip_runtime.h>

// Problem constants (B=4, G=512, Dim=384, N=25088, img 224, kernel_size 8)
#define BATCH 4
#define NGRP  512
#define DIM   384
#define NPTS  25088
#define IMG   224
#define KS    8
#define HOUT  28
#define LIVE_HO 14        // N = 112*224 -> pooled rows 0..13 live, 14..27 zero

#define GB    8
#define NBIN  (GB * GB * GB)       // 512
#define HBIN  0.125f
#define PSTRIDE 388                // psum row stride (floats)

// ---- workspace layout (bytes) ----
// per batch (stride WS_BSTRIDE):
//   cbin   float4[512]  : x,y,z,as_float(center idx)      8192
//   cstart int[513]     : CSR offsets                     2052 -> pad 2064
//   pbin   float4[25088]: x,y,z,as_float(point id)      401408
//   pstart int[513]                                       2052 -> pad 2064
#define WS_CB 0
#define WS_CS 8192
#define WS_PB (8192 + 2064)
#define WS_PS (WS_PB + 401408)
#define WS_BSTRIDE (WS_PS + 2064)          // 413728
#define WS_PAIRS (BATCH * WS_BSTRIDE)      // int2 pairs[B*N*3] after batch blocks

__device__ __forceinline__ bool kvlt(float da, int ia, float db, int ib) {
    // strict total order on (d2, center index) — lax.top_k stable-tie semantics
    return (da < db) || ((da == db) && (ia < ib));
}

__device__ __forceinline__ int bin_of(float v) {
    int i = (int)(v * 8.0f);                // *8 exact (pow2), inputs in [0,1)
    return min(max(i, 0), GB - 1);
}

// ===========================================================================
// Pre-kernel 1: bin the 512 centers of one batch into the 8^3 grid (CSR).
// Within-bin order nondeterministic (atomics) — harmless: selection is
// (d2,idx)-lex order-invariant.
// ===========================================================================
__global__ __launch_bounds__(512) void prebin_kernel(
    const float* __restrict__ centers,   // (B, G, 3)
    char* __restrict__ ws)
{
    const int b = blockIdx.x;
    const int t = threadIdx.x;

    __shared__ int cnt[NBIN];
    __shared__ int cur[NBIN];
    __shared__ int sstart[NBIN];
    __shared__ int wsum[8];

    cnt[t] = 0; cur[t] = 0;
    __syncthreads();

    const float x = centers[((size_t)b * NGRP + t) * 3 + 0];
    const float y = centers[((size_t)b * NGRP + t) * 3 + 1];
    const float z = centers[((size_t)b * NGRP + t) * 3 + 2];
    const int bin = (bin_of(z) * GB + bin_of(y)) * GB + bin_of(x);
    atomicAdd(&cnt[bin], 1);
    __syncthreads();

    const int lane = t & 63;
    const int wid  = t >> 6;
    const int v = cnt[t];
    int inc = v;
    #pragma unroll
    for (int d = 1; d < 64; d <<= 1) {
        const int nv = __shfl_up(inc, d, 64);
        if (lane >= d) inc += nv;
    }
    if (lane == 63) wsum[wid] = inc;
    __syncthreads();
    if (t == 0) {
        int acc = 0;
        #pragma unroll
        for (int i = 0; i < 8; ++i) { const int c = wsum[i]; wsum[i] = acc; acc += c; }
    }
    __syncthreads();
    const int startv = wsum[wid] + inc - v;

    char* wb = ws + (size_t)b * WS_BSTRIDE;
    float4* cb4 = (float4*)(wb + WS_CB);
    int*    cs  = (int*)(wb + WS_CS);

    cs[t] = startv;
    if (t == 0) cs[NBIN] = NGRP;
    sstart[t] = startv;
    __syncthreads();

    const int pos = sstart[bin] + atomicAdd(&cur[bin], 1);
    cb4[pos] = make_float4(x, y, z, __int_as_float(t));
}

// ===========================================================================
// Pre-kernel 2: bin the 25088 points of one batch into the same grid (CSR).
// ===========================================================================
__global__ __launch_bounds__(1024) void binpts_kernel(
    const float* __restrict__ points,    // (B, N, 3)
    char* __restrict__ ws)
{
    const int b = blockIdx.x;
    const int t = threadIdx.x;

    __shared__ int cnt[NBIN];
    __shared__ int cur[NBIN];
    __shared__ int sstart[NBIN];
    __shared__ int wsum[8];

    if (t < NBIN) { cnt[t] = 0; cur[t] = 0; }
    __syncthreads();

    const float* pb = points + (size_t)b * NPTS * 3;
    for (int n = t; n < NPTS; n += 1024) {
        const float x = pb[n * 3 + 0];
        const float y = pb[n * 3 + 1];
        const float z = pb[n * 3 + 2];
        const int bin = (bin_of(z) * GB + bin_of(y)) * GB + bin_of(x);
        atomicAdd(&cnt[bin], 1);
    }
    __syncthreads();

    const int lane = t & 63;
    const int wid  = t >> 6;
    const int v = (t < NBIN) ? cnt[t] : 0;
    int inc = v;
    #pragma unroll
    for (int d = 1; d < 64; d <<= 1) {
        const int nv = __shfl_up(inc, d, 64);
        if (lane >= d) inc += nv;
    }
    if (lane == 63 && wid < 8) wsum[wid] = inc;
    __syncthreads();
    if (t == 0) {
        int acc = 0;
        #pragma unroll
        for (int i = 0; i < 8; ++i) { const int c = wsum[i]; wsum[i] = acc; acc += c; }
    }
    __syncthreads();

    char* wb = ws + (size_t)b * WS_BSTRIDE;
    float4* pb4 = (float4*)(wb + WS_PB);
    int*    ps  = (int*)(wb + WS_PS);

    if (t < NBIN) {
        const int startv = wsum[wid] + inc - v;
        sstart[t] = startv;
        ps[t] = startv;
    }
    if (t == 0) ps[NBIN] = NPTS;
    __syncthreads();

    for (int n = t; n < NPTS; n += 1024) {
        const float x = pb[n * 3 + 0];
        const float y = pb[n * 3 + 1];
        const float z = pb[n * 3 + 2];
        const int bin = (bin_of(z) * GB + bin_of(y)) * GB + bin_of(x);
        const int pos = sstart[bin] + atomicAdd(&cur[bin], 1);
        pb4[pos] = make_float4(x, y, z, __int_as_float(n));
    }
}

// ===========================================================================
// NN kernel: one WAVE per (batch, bin) — 4 waves/block share staged centers.
// All lanes of a wave share one query bin -> shell walk is wave-uniform and
// every candidate read is an LDS same-address broadcast (no conflicts, the
// R8 failure mode). Exactness: stop after shell s only when
// e2 < (s/8)^2 - 1e-5; unvisited centers have formula-d2 >= (s/8)^2 - 6e-7
// > e2, so they provably cannot alter the (d2,idx)-lex top-3. Worst case
// the walk degenerates to the full exact scan. d2 op sequence and weight
// epilogue bit-identical to rounds 4..7.
// ===========================================================================
__global__ __launch_bounds__(256) void nn_kernel(
    const char* __restrict__ ws,
    int2* __restrict__ pairs_g)          // (B, N, 3) packed (idx, w bits)
{
    const int b = blockIdx.y;
    const int t = threadIdx.x;
    const int wid  = t >> 6;
    const int lane = t & 63;

    __shared__ float4 scb[NGRP];         // 8 KB: centers x,y,z,as_float(idx)
    __shared__ int    scs[NBIN + 1];

    const char* wb = ws + (size_t)b * WS_BSTRIDE;
    const float4* g4 = (const float4*)(wb + WS_CB);
    const int*    gs = (const int*)(wb + WS_CS);
    const float4* pb4 = (const float4*)(wb + WS_PB);
    const int*    ps  = (const int*)(wb + WS_PS);

    for (int i = t; i < NGRP; i += 256) scb[i] = g4[i];
    for (int i = t; i < NBIN + 1; i += 256) scs[i] = gs[i];
    __syncthreads();

    const int bin = blockIdx.x * 4 + wid;
    const int bx = bin & 7;
    const int by = (bin >> 3) & 7;
    const int bz = bin >> 6;

    const int pstart = ps[bin];
    const int pend   = ps[bin + 1];

    for (int chunk = pstart; chunk < pend; chunk += 64) {
        const int me = chunk + lane;
        const bool live = (me < pend);

        float px = 0.0f, py = 0.0f, pz = 0.0f, tn = 0.0f;
        int pid = 0;
        if (live) {
            const float4 p = pb4[me];
            px = p.x; py = p.y; pz = p.z;
            pid = __float_as_int(p.w);
            tn = __fadd_rn(__fadd_rn(__fmul_rn(px, px), __fmul_rn(py, py)),
                           __fmul_rn(pz, pz));
        }

        float e0 = 1e30f, e1 = 1e30f, e2 = 1e30f;
        int   j0 = 0,     j1 = 0,     j2 = 0;
        bool done = !live;

        for (int s = 0; s < GB; ++s) {
            if (__all(done)) break;
            // shell s around (bx,by,bz): wave-uniform walk
            for (int dz = -s; dz <= s; ++dz) {
                const int zz = bz + dz;
                if ((unsigned)zz >= GB) continue;
                const bool zface = (dz == -s) || (dz == s);
                for (int dy = -s; dy <= s; ++dy) {
                    const int yy = by + dy;
                    if ((unsigned)yy >= GB) continue;
                    const bool yface = zface || (dy == -s) || (dy == s);
                    for (int dx = -s; dx <= s; ++dx) {
                        if (!yface && dx != -s && dx != s) continue;
                        const int xx = bx + dx;
                        if ((unsigned)xx >= GB) continue;
                        const int bin2 = (zz * GB + yy) * GB + xx;
                        const int c1 = scs[bin2 + 1];
                        for (int c = scs[bin2]; c < c1; ++c) {
                            const float4 cc = scb[c];     // broadcast read
                            const int sidx = __float_as_int(cc.w);
                            const float ss = __fadd_rn(
                                __fadd_rn(__fmul_rn(cc.x, cc.x),
                                          __fmul_rn(cc.y, cc.y)),
                                __fmul_rn(cc.z, cc.z));
                            float acc = __fmul_rn(px, cc.x);
                            acc = fmaf(py, cc.y, acc);
                            acc = fmaf(pz, cc.z, acc);
                            const float dd = __fsub_rn(__fadd_rn(tn, ss),
                                                       __fmul_rn(2.0f, acc));
                            const bool lt2 = kvlt(dd, sidx, e2, j2);
                            const bool lt1 = kvlt(dd, sidx, e1, j1);
                            const bool lt0 = kvlt(dd, sidx, e0, j0);
                            e2 = lt1 ? e1 : (lt2 ? dd : e2);
                            j2 = lt1 ? j1 : (lt2 ? sidx : j2);
                            e1 = lt0 ? e0 : (lt1 ? dd : e1);
                            j1 = lt0 ? j0 : (lt1 ? sidx : j1);
                            e0 = lt0 ? dd : e0;
                            j0 = lt0 ? sidx : j0;
                        }
                    }
                }
            }
            const float cut = HBIN * (float)s;
            if (e2 < cut * cut - 1e-5f) done = true;
        }

        if (live) {
            const float f0 = fmaxf(e0, 1e-10f);
            const float f1 = fmaxf(e1, 1e-10f);
            const float f2 = fmaxf(e2, 1e-10f);
            const float r0 = 1.0f / f0, r1 = 1.0f / f1, r2 = 1.0f / f2;
            const float inv = 1.0f / __fadd_rn(__fadd_rn(r0, r1), r2);
            int2* pr = pairs_g + ((size_t)b * NPTS + pid) * 3;
            pr[0] = make_int2(j0, __float_as_int(r0 * inv));
            pr[1] = make_int2(j1, __float_as_int(r1 * inv));
            pr[2] = make_int2(j2, __float_as_int(r2 * inv));
        }
    }
}

// ===========================================================================
// Interp + 8x8 pool: round-6 B kernel verbatim (same j-order and reduction
// tree -> bit-identical), live cells only; dead region covered by memset.
// ===========================================================================
__global__ __launch_bounds__(192) void interp_pool_kernel(
    const float* __restrict__ feats,     // (B, G, DIM)
    const int2*  __restrict__ pairs_g,   // (B, N, 3)
    float* __restrict__ out)             // (B, DIM, 28, 28)
{
    const int cell = blockIdx.x;         // 0..391 (all live)
    const int b    = blockIdx.y;
    const int ho   = cell / HOUT;
    const int wo   = cell - ho * HOUT;
    const int t    = threadIdx.x;

    __shared__ int2 pairs[192];
    __shared__ __align__(16) float psum[4 * PSTRIDE];

    {
        const int p = t / 3;
        const int k = t - p * 3;
        const int n = (ho * KS + (p >> 3)) * IMG + wo * KS + (p & 7);
        pairs[t] = pairs_g[((size_t)b * NPTS + n) * 3 + k];
    }
    __syncthreads();

    {
        const int jslice = t / 48;
        const int dc     = t - jslice * 48;
        const int d0     = dc * 8;

        const float* fbase = feats + (size_t)b * NGRP * DIM + d0;
        float acc[8];
        #pragma unroll
        for (int dd = 0; dd < 8; ++dd) acc[dd] = 0.0f;

        const int jb = jslice * 48;
        #pragma unroll 4
        for (int jj = 0; jj < 48; ++jj) {
            const int2 pr = pairs[jb + jj];
            const float wg = __int_as_float(pr.y);
            const float4* fp = (const float4*)(fbase + (size_t)pr.x * DIM);
            const float4 f0 = fp[0];
            const float4 f1 = fp[1];
            acc[0] = fmaf(wg, f0.x, acc[0]);
            acc[1] = fmaf(wg, f0.y, acc[1]);
            acc[2] = fmaf(wg, f0.z, acc[2]);
            acc[3] = fmaf(wg, f0.w, acc[3]);
            acc[4] = fmaf(wg, f1.x, acc[4]);
            acc[5] = fmaf(wg, f1.y, acc[5]);
            acc[6] = fmaf(wg, f1.z, acc[6]);
            acc[7] = fmaf(wg, f1.w, acc[7]);
        }

        float4* pp = (float4*)&psum[jslice * PSTRIDE + d0];
        pp[0] = make_float4(acc[0], acc[1], acc[2], acc[3]);
        pp[1] = make_float4(acc[4], acc[5], acc[6], acc[7]);
    }
    __syncthreads();

    {
        const size_t obase = ((size_t)b * DIM) * (HOUT * HOUT) + (size_t)ho * HOUT + wo;
        const int da = t;
        const int db = t + 192;
        const float sa = __fadd_rn(__fadd_rn(__fadd_rn(psum[0 * PSTRIDE + da],
                                                       psum[1 * PSTRIDE + da]),
                                             psum[2 * PSTRIDE + da]),
                                   psum[3 * PSTRIDE + da]);
        const float sb = __fadd_rn(__fadd_rn(__fadd_rn(psum[0 * PSTRIDE + db],
                                                       psum[1 * PSTRIDE + db]),
                                             psum[2 * PSTRIDE + db]),
                                   psum[3 * PSTRIDE + db]);
        out[obase + (size_t)da * (HOUT * HOUT)] = sa * (1.0f / 64.0f);
        out[obase + (size_t)db * (HOUT * HOUT)] = sb * (1.0f / 64.0f);
    }
}

// ---------------------------------------------------------------------------
extern "C" void kernel_launch(void* const* d_in, const int* in_sizes, int n_in,
                              void* d_out, int out_size, void* d_ws, size_t ws_size,
                              hipStream_t stream) {
    const float* group_features  = (const float*)d_in[0];  // (B, G, DIM)
    const float* group_centers   = (const float*)d_in[1];  // (B, G, 3)
    const float* original_points = (const float*)d_in[2];  // (B, N, 3)

    float* out = (float*)d_out;                            // (B, DIM, 28, 28)
    char*  ws  = (char*)d_ws;
    int2*  pairs_g = (int2*)(ws + WS_PAIRS);

    hipMemsetAsync(out, 0, (size_t)out_size * sizeof(float), stream);

    prebin_kernel<<<BATCH, 512, 0, stream>>>(group_centers, ws);
    binpts_kernel<<<BATCH, 1024, 0, stream>>>(original_points, ws);

    {
        dim3 grid(NBIN / 4, BATCH);                        // wave per (batch, bin)
        nn_kernel<<<grid, 256, 0, stream>>>(ws, pairs_g);
    }
    {
        dim3 grid(LIVE_HO * HOUT, BATCH);                  // (392, 4) live cells
        interp_pool_kernel<<<grid, 192, 0, stream>>>(group_features, pairs_g, out);
    }
}

// Round 10
// 193.184 us; speedup vs baseline: 1.0591x; 1.0591x over previous
//
#include <hip/hip_runtime.h>

// Problem constants (B=4, G=512, Dim=384, N=25088, img 224, kernel_size 8)
#define BATCH 4
#define NGRP  512
#define DIM   384
#define NPTS  25088
#define IMG   224
#define KS    8
#define HOUT  28
#define LIVE_HO 14        // pooled rows 0..13 live, 14..27 exactly zero

#define GB    8
#define NBIN  (GB * GB * GB)       // 512
#define NSLICE 8
#define SLICE (NPTS / NSLICE)      // 3136
#define CAP   256                  // per-wave candidate buffer capacity
#define BOUND (0.0625f - 1e-5f)    // safe-stop: unvisited formula-d2 >= 0.0625-6e-7
#define PSTRIDE 388                // psum row stride (floats)

// ---- workspace layout (bytes), per batch ----
#define WS_CB 0                          // float4 cbin[512]        8192
#define WS_CS 8192                       // int cstart[513]         2052 -> pad
#define WS_PS 10256                      // int pstart[8][513]     16416
#define WS_PB 26672                      // float4 pbin[25088]    401408
#define WS_BSTRIDE 428080
#define WS_PAIRS (BATCH * WS_BSTRIDE)    // int2 pairs[B*N*3] after batch blocks

__device__ __forceinline__ bool kvlt(float da, int ia, float db, int ib) {
    // strict total order on (d2, center idx) — lax.top_k stable-tie semantics
    return (da < db) || ((da == db) && (ia < ib));
}

__device__ __forceinline__ int bin_of(float v) {
    int i = (int)(v * 8.0f);             // *8 exact (pow2), inputs in [0,1)
    return min(max(i, 0), GB - 1);
}

// ===========================================================================
// Binning kernel, grid (9, BATCH) x 512 thr:
//   blockIdx.x == 8 : bin the 512 centers into an 8^3 CSR (as in R9 prebin)
//   blockIdx.x == s : bin point slice [s*3136, (s+1)*3136) into a per-slice
//                     CSR (8 slice blocks run in parallel -> fixes R9's
//                     4-blocks-on-4-CUs binpts serialization)
// Within-bin order nondeterministic (atomics) — harmless: selection is
// (d2,idx)-lex order-invariant.
// ===========================================================================
__global__ __launch_bounds__(512) void bin_kernel(
    const float* __restrict__ centers,   // (B, G, 3)
    const float* __restrict__ points,    // (B, N, 3)
    char* __restrict__ ws)
{
    const int role = blockIdx.x;         // 0..7 point slices, 8 = centers
    const int b    = blockIdx.y;
    const int t    = threadIdx.x;

    __shared__ int cnt[NBIN];
    __shared__ int cur[NBIN];
    __shared__ int sstart[NBIN];
    __shared__ int wsum[8];

    cnt[t] = 0; cur[t] = 0;
    __syncthreads();

    char* wb = ws + (size_t)b * WS_BSTRIDE;

    if (role == NSLICE) {
        // ---------------- centers ----------------
        const float x = centers[((size_t)b * NGRP + t) * 3 + 0];
        const float y = centers[((size_t)b * NGRP + t) * 3 + 1];
        const float z = centers[((size_t)b * NGRP + t) * 3 + 2];
        const int bin = (bin_of(z) * GB + bin_of(y)) * GB + bin_of(x);
        atomicAdd(&cnt[bin], 1);
        __syncthreads();

        const int lane = t & 63, wid = t >> 6;
        const int v = cnt[t];
        int inc = v;
        #pragma unroll
        for (int d = 1; d < 64; d <<= 1) {
            const int nv = __shfl_up(inc, d, 64);
            if (lane >= d) inc += nv;
        }
        if (lane == 63) wsum[wid] = inc;
        __syncthreads();
        if (t == 0) {
            int acc = 0;
            #pragma unroll
            for (int i = 0; i < 8; ++i) { const int c = wsum[i]; wsum[i] = acc; acc += c; }
        }
        __syncthreads();
        const int startv = wsum[wid] + inc - v;

        float4* cb4 = (float4*)(wb + WS_CB);
        int*    cs  = (int*)(wb + WS_CS);
        cs[t] = startv;
        if (t == 0) cs[NBIN] = NGRP;
        sstart[t] = startv;
        __syncthreads();
        const int pos = sstart[bin] + atomicAdd(&cur[bin], 1);
        cb4[pos] = make_float4(x, y, z, __int_as_float(t));
    } else {
        // ---------------- point slice ----------------
        const int n0 = role * SLICE;
        const float* pb = points + ((size_t)b * NPTS + n0) * 3;
        for (int n = t; n < SLICE; n += 512) {
            const float x = pb[n * 3 + 0];
            const float y = pb[n * 3 + 1];
            const float z = pb[n * 3 + 2];
            const int bin = (bin_of(z) * GB + bin_of(y)) * GB + bin_of(x);
            atomicAdd(&cnt[bin], 1);
        }
        __syncthreads();

        const int lane = t & 63, wid = t >> 6;
        const int v = cnt[t];
        int inc = v;
        #pragma unroll
        for (int d = 1; d < 64; d <<= 1) {
            const int nv = __shfl_up(inc, d, 64);
            if (lane >= d) inc += nv;
        }
        if (lane == 63) wsum[wid] = inc;
        __syncthreads();
        if (t == 0) {
            int acc = 0;
            #pragma unroll
            for (int i = 0; i < 8; ++i) { const int c = wsum[i]; wsum[i] = acc; acc += c; }
        }
        __syncthreads();
        const int startv = wsum[wid] + inc - v;

        int* ps = (int*)(wb + WS_PS) + role * (NBIN + 1);
        ps[t] = n0 + startv;
        if (t == 0) ps[NBIN] = n0 + SLICE;
        sstart[t] = startv;
        __syncthreads();

        float4* pb4 = (float4*)(wb + WS_PB);
        for (int n = t; n < SLICE; n += 512) {
            const float x = pb[n * 3 + 0];
            const float y = pb[n * 3 + 1];
            const float z = pb[n * 3 + 2];
            const int bin = (bin_of(z) * GB + bin_of(y)) * GB + bin_of(x);
            const int pos = n0 + sstart[bin] + atomicAdd(&cur[bin], 1);
            pb4[pos] = make_float4(x, y, z, __int_as_float(n0 + n));
        }
    }
}

// ===========================================================================
// NN kernel: one WAVE per (batch, bin); 4 waves/block share staged tables.
// The Chebyshev<=2 region (<=25 CSR row-segments, ~127 centers) is flattened
// ONCE per wave into a contiguous LDS buffer (cooperative copy, ss computed
// with the reference op sequence). The hot loop is then a counted loop over
// contiguous LDS with wave-uniform BROADCAST reads, 2 interleaved top-3
// states (even/odd candidates) merged by the proven R5 sorted-triple merge
// -> (d2,idx)-lex order-invariant -> bit-identical selection.
// Exactness: accept only if e2 < 0.0625-1e-5 (unvisited centers have
// formula-d2 >= 0.0625-6e-7); failing lanes (and buffer overflow) fall back
// to a full 512-center rescan with reset state.
// ===========================================================================
__global__ __launch_bounds__(256) void nn_kernel(
    const char* __restrict__ ws,
    int2* __restrict__ pairs_g)          // (B, N, 3) packed (idx, w bits)
{
    const int b = blockIdx.y;
    const int t = threadIdx.x;
    const int wid  = t >> 6;
    const int lane = t & 63;

    __shared__ float4 scb[NGRP];                 // centers x,y,z,as_float(idx)
    __shared__ int    scs[NBIN + 1];
    __shared__ int    sps[NSLICE * (NBIN + 1)];  // per-slice point CSR
    __shared__ float4 cand[4][CAP];              // per-wave candidates x,y,z,ss
    __shared__ int    candi[4][CAP];             // per-wave candidate idx

    const char* wb = ws + (size_t)b * WS_BSTRIDE;
    const float4* g4  = (const float4*)(wb + WS_CB);
    const int*    gs  = (const int*)(wb + WS_CS);
    const int*    gps = (const int*)(wb + WS_PS);
    const float4* pb4 = (const float4*)(wb + WS_PB);

    for (int i = t; i < NGRP; i += 256) scb[i] = g4[i];
    for (int i = t; i < NBIN + 1; i += 256) scs[i] = gs[i];
    for (int i = t; i < NSLICE * (NBIN + 1); i += 256) sps[i] = gps[i];
    __syncthreads();

    const int bin = blockIdx.x * 4 + wid;
    const int bx = bin & 7;
    const int by = (bin >> 3) & 7;
    const int bz = bin >> 6;

    // ---- this bin's points across the 8 slices (wave-uniform) ----
    int base_s[NSLICE], cnt_s[NSLICE], pre_s[NSLICE];
    int npts = 0;
    #pragma unroll
    for (int s = 0; s < NSLICE; ++s) {
        base_s[s] = sps[s * (NBIN + 1) + bin];
        cnt_s[s]  = sps[s * (NBIN + 1) + bin + 1] - base_s[s];
        pre_s[s]  = npts;
        npts += cnt_s[s];
    }
    if (npts == 0) return;   // whole wave idle; block barrier already passed

    // ---- flatten the Chebyshev<=2 region into contiguous LDS ----
    const int x0 = max(bx - 2, 0), x1 = min(bx + 2, GB - 1);
    const int y0 = max(by - 2, 0), y1 = min(by + 2, GB - 1);
    const int z0 = max(bz - 2, 0), z1 = min(bz + 2, GB - 1);
    const int ny = y1 - y0 + 1;
    const int nrows = (z1 - z0 + 1) * ny;

    int segStart = 0, segLen = 0;
    if (lane < nrows) {
        const int zz = z0 + lane / ny;
        const int yy = y0 + lane - (lane / ny) * ny;
        const int rowbase = (zz * GB + yy) * GB;
        segStart = scs[rowbase + x0];
        segLen   = scs[rowbase + x1 + 1] - segStart;
    }
    int pre = segLen;
    #pragma unroll
    for (int d = 1; d < 64; d <<= 1) {
        const int nv = __shfl_up(pre, d, 64);
        if (lane >= d) pre += nv;
    }
    const int dst   = pre - segLen;
    const int ncand = __shfl(pre, nrows - 1, 64);
    const bool overflow = (ncand > CAP - 1);

    if (!overflow) {
        if (lane < nrows) {
            for (int k = 0; k < segLen; ++k) {
                const float4 cc = scb[segStart + k];
                const float ss = __fadd_rn(__fadd_rn(__fmul_rn(cc.x, cc.x),
                                                     __fmul_rn(cc.y, cc.y)),
                                           __fmul_rn(cc.z, cc.z));
                cand[wid][dst + k]  = make_float4(cc.x, cc.y, cc.z, ss);
                candi[wid][dst + k] = __float_as_int(cc.w);
            }
        }
        if (lane == 0) {   // sentinel (never selected) for odd ncand
            cand[wid][ncand]  = make_float4(0.0f, 0.0f, 0.0f, 1e30f);
            candi[wid][ncand] = 0x7fffffff;
        }
    }
    __threadfence_block();   // wave-local LDS writes -> reads

    // ---- process this bin's points, 64 per chunk ----
    for (int base = 0; base < npts; base += 64) {
        const int me = base + lane;
        const bool live = (me < npts);

        float px = 0.0f, py = 0.0f, pz = 0.0f, tn = 0.0f;
        int pid = 0;
        if (live) {
            int s = 0, rem = me;
            #pragma unroll
            for (int k = 0; k < NSLICE; ++k) {
                if (me >= pre_s[k] && cnt_s[k] > 0) { s = k; rem = me - pre_s[k]; }
            }
            const float4 p = pb4[base_s[s] + rem];
            px = p.x; py = p.y; pz = p.z;
            pid = __float_as_int(p.w);
            tn = __fadd_rn(__fadd_rn(__fmul_rn(px, px), __fmul_rn(py, py)),
                           __fmul_rn(pz, pz));
        }

        float e0 = 1e30f, e1 = 1e30f, e2 = 1e30f;
        int   j0 = 0,     j1 = 0,     j2 = 0;

        if (!overflow) {
            // two interleaved states over even/odd candidates
            float a0 = 1e30f, a1 = 1e30f, a2 = 1e30f;
            int   u0 = 0,     u1 = 0,     u2 = 0;
            float f0 = 1e30f, f1 = 1e30f, f2 = 1e30f;
            int   g0 = 0,     g1 = 0,     g2 = 0;

            #pragma unroll 2
            for (int c = 0; c < ncand; c += 2) {
                {
                    const float4 cc = cand[wid][c];
                    const int sidx  = candi[wid][c];
                    float acc = __fmul_rn(px, cc.x);
                    acc = fmaf(py, cc.y, acc);
                    acc = fmaf(pz, cc.z, acc);
                    const float dd = __fsub_rn(__fadd_rn(tn, cc.w),
                                               __fmul_rn(2.0f, acc));
                    const bool lt2 = kvlt(dd, sidx, a2, u2);
                    const bool lt1 = kvlt(dd, sidx, a1, u1);
                    const bool lt0 = kvlt(dd, sidx, a0, u0);
                    a2 = lt1 ? a1 : (lt2 ? dd : a2);
                    u2 = lt1 ? u1 : (lt2 ? sidx : u2);
                    a1 = lt0 ? a0 : (lt1 ? dd : a1);
                    u1 = lt0 ? u0 : (lt1 ? sidx : u1);
                    a0 = lt0 ? dd : a0;
                    u0 = lt0 ? sidx : u0;
                }
                {
                    const float4 cc = cand[wid][c + 1];
                    const int sidx  = candi[wid][c + 1];
                    float acc = __fmul_rn(px, cc.x);
                    acc = fmaf(py, cc.y, acc);
                    acc = fmaf(pz, cc.z, acc);
                    const float dd = __fsub_rn(__fadd_rn(tn, cc.w),
                                               __fmul_rn(2.0f, acc));
                    const bool lt2 = kvlt(dd, sidx, f2, g2);
                    const bool lt1 = kvlt(dd, sidx, f1, g1);
                    const bool lt0 = kvlt(dd, sidx, f0, g0);
                    f2 = lt1 ? f1 : (lt2 ? dd : f2);
                    g2 = lt1 ? g1 : (lt2 ? sidx : g2);
                    f1 = lt0 ? f0 : (lt1 ? dd : f1);
                    g1 = lt0 ? g0 : (lt1 ? sidx : g1);
                    f0 = lt0 ? dd : f0;
                    g0 = lt0 ? sidx : g0;
                }
            }

            // merge the two sorted triples (R5 merge, proven)
            const bool c0 = kvlt(a0, u0, f0, g0);
            const float X0 = c0 ? a0 : f0;  const int U0 = c0 ? u0 : g0;
            const float X1 = c0 ? a1 : f1;  const int U1 = c0 ? u1 : g1;
            const float X2 = c0 ? a2 : f2;  const int U2 = c0 ? u2 : g2;
            const float Y0 = c0 ? f0 : a0;  const int V0 = c0 ? g0 : u0;
            const float Y1 = c0 ? f1 : a1;  const int V1 = c0 ? g1 : u1;
            const bool c1 = kvlt(X1, U1, Y0, V0);
            const float r1 = c1 ? X1 : Y0;  const int s1 = c1 ? U1 : V0;
            const bool c2a = kvlt(X2, U2, Y0, V0);
            const float r2a = c2a ? X2 : Y0; const int s2a = c2a ? U2 : V0;
            const bool c2b = kvlt(X1, U1, Y1, V1);
            const float r2b = c2b ? X1 : Y1; const int s2b = c2b ? U1 : V1;
            e0 = X0;  j0 = U0;
            e1 = r1;  j1 = s1;
            e2 = c1 ? r2a : r2b;
            j2 = c1 ? s2a : s2b;
        }

        // safe-stop check; failing (or overflow) live lanes rescan all 512
        const bool ok = !live || (!overflow && (e2 < BOUND));
        if (__any(!ok)) {
            if (!ok) {
                e0 = 1e30f; e1 = 1e30f; e2 = 1e30f;
                j0 = 0;     j1 = 0;     j2 = 0;
            }
            for (int c = 0; c < NGRP; ++c) {
                const float4 cc = scb[c];            // broadcast
                if (!ok) {
                    const int sidx = __float_as_int(cc.w);
                    const float ss = __fadd_rn(__fadd_rn(__fmul_rn(cc.x, cc.x),
                                                         __fmul_rn(cc.y, cc.y)),
                                               __fmul_rn(cc.z, cc.z));
                    float acc = __fmul_rn(px, cc.x);
                    acc = fmaf(py, cc.y, acc);
                    acc = fmaf(pz, cc.z, acc);
                    const float dd = __fsub_rn(__fadd_rn(tn, ss),
                                               __fmul_rn(2.0f, acc));
                    const bool lt2 = kvlt(dd, sidx, e2, j2);
                    const bool lt1 = kvlt(dd, sidx, e1, j1);
                    const bool lt0 = kvlt(dd, sidx, e0, j0);
                    e2 = lt1 ? e1 : (lt2 ? dd : e2);
                    j2 = lt1 ? j1 : (lt2 ? sidx : j2);
                    e1 = lt0 ? e0 : (lt1 ? dd : e1);
                    j1 = lt0 ? j0 : (lt1 ? sidx : j1);
                    e0 = lt0 ? dd : e0;
                    j0 = lt0 ? sidx : j0;
                }
            }
        }

        if (live) {
            const float f0 = fmaxf(e0, 1e-10f);
            const float f1 = fmaxf(e1, 1e-10f);
            const float f2 = fmaxf(e2, 1e-10f);
            const float r0 = 1.0f / f0, r1 = 1.0f / f1, r2 = 1.0f / f2;
            const float inv = 1.0f / __fadd_rn(__fadd_rn(r0, r1), r2);
            int2* pr = pairs_g + ((size_t)b * NPTS + pid) * 3;
            pr[0] = make_int2(j0, __float_as_int(r0 * inv));
            pr[1] = make_int2(j1, __float_as_int(r1 * inv));
            pr[2] = make_int2(j2, __float_as_int(r2 * inv));
        }
    }
}

// ===========================================================================
// Interp + 8x8 pool: round-6 B kernel verbatim (same j-order and reduction
// tree -> bit-identical), live cells only; dead region covered by memset.
// ===========================================================================
__global__ __launch_bounds__(192) void interp_pool_kernel(
    const float* __restrict__ feats,     // (B, G, DIM)
    const int2*  __restrict__ pairs_g,   // (B, N, 3)
    float* __restrict__ out)             // (B, DIM, 28, 28)
{
    const int cell = blockIdx.x;         // 0..391 (all live)
    const int b    = blockIdx.y;
    const int ho   = cell / HOUT;
    const int wo   = cell - ho * HOUT;
    const int t    = threadIdx.x;

    __shared__ int2 pairs[192];
    __shared__ __align__(16) float psum[4 * PSTRIDE];

    {
        const int p = t / 3;
        const int k = t - p * 3;
        const int n = (ho * KS + (p >> 3)) * IMG + wo * KS + (p & 7);
        pairs[t] = pairs_g[((size_t)b * NPTS + n) * 3 + k];
    }
    __syncthreads();

    {
        const int jslice = t / 48;
        const int dc     = t - jslice * 48;
        const int d0     = dc * 8;

        const float* fbase = feats + (size_t)b * NGRP * DIM + d0;
        float acc[8];
        #pragma unroll
        for (int dd = 0; dd < 8; ++dd) acc[dd] = 0.0f;

        const int jb = jslice * 48;
        #pragma unroll 4
        for (int jj = 0; jj < 48; ++jj) {
            const int2 pr = pairs[jb + jj];
            const float wg = __int_as_float(pr.y);
            const float4* fp = (const float4*)(fbase + (size_t)pr.x * DIM);
            const float4 f0 = fp[0];
            const float4 f1 = fp[1];
            acc[0] = fmaf(wg, f0.x, acc[0]);
            acc[1] = fmaf(wg, f0.y, acc[1]);
            acc[2] = fmaf(wg, f0.z, acc[2]);
            acc[3] = fmaf(wg, f0.w, acc[3]);
            acc[4] = fmaf(wg, f1.x, acc[4]);
            acc[5] = fmaf(wg, f1.y, acc[5]);
            acc[6] = fmaf(wg, f1.z, acc[6]);
            acc[7] = fmaf(wg, f1.w, acc[7]);
        }

        float4* pp = (float4*)&psum[jslice * PSTRIDE + d0];
        pp[0] = make_float4(acc[0], acc[1], acc[2], acc[3]);
        pp[1] = make_float4(acc[4], acc[5], acc[6], acc[7]);
    }
    __syncthreads();

    {
        const size_t obase = ((size_t)b * DIM) * (HOUT * HOUT) + (size_t)ho * HOUT + wo;
        const int da = t;
        const int db = t + 192;
        const float sa = __fadd_rn(__fadd_rn(__fadd_rn(psum[0 * PSTRIDE + da],
                                                       psum[1 * PSTRIDE + da]),
                                             psum[2 * PSTRIDE + da]),
                                   psum[3 * PSTRIDE + da]);
        const float sb = __fadd_rn(__fadd_rn(__fadd_rn(psum[0 * PSTRIDE + db],
                                                       psum[1 * PSTRIDE + db]),
                                             psum[2 * PSTRIDE + db]),
                                   psum[3 * PSTRIDE + db]);
        out[obase + (size_t)da * (HOUT * HOUT)] = sa * (1.0f / 64.0f);
        out[obase + (size_t)db * (HOUT * HOUT)] = sb * (1.0f / 64.0f);
    }
}

// ---------------------------------------------------------------------------
extern "C" void kernel_launch(void* const* d_in, const int* in_sizes, int n_in,
                              void* d_out, int out_size, void* d_ws, size_t ws_size,
                              hipStream_t stream) {
    const float* group_features  = (const float*)d_in[0];  // (B, G, DIM)
    const float* group_centers   = (const float*)d_in[1];  // (B, G, 3)
    const float* original_points = (const float*)d_in[2];  // (B, N, 3)

    float* out = (float*)d_out;                            // (B, DIM, 28, 28)
    char*  ws  = (char*)d_ws;
    int2*  pairs_g = (int2*)(ws + WS_PAIRS);

    hipMemsetAsync(out, 0, (size_t)out_size * sizeof(float), stream);

    {
        dim3 grid(NSLICE + 1, BATCH);                      // (9, 4)
        bin_kernel<<<grid, 512, 0, stream>>>(group_centers, original_points, ws);
    }
    {
        dim3 grid(NBIN / 4, BATCH);                        // wave per (batch, bin)
        nn_kernel<<<grid, 256, 0, stream>>>(ws, pairs_g);
    }
    {
        dim3 grid(LIVE_HO * HOUT, BATCH);                  // (392, 4) live cells
        interp_pool_kernel<<<grid, 192, 0, stream>>>(group_features, pairs_g, out);
    }
}